// Round 17
// baseline (2996.341 us; speedup 1.0000x reference)
//
#include <hip/hip_runtime.h>
#include <hip/hip_bf16.h>

#define B_ 4096
#define I_ 1024
#define H_ 2048
#define O_ 1024
#define K1 (I_ + H_)   // 3072
#define N1 (4 * H_)    // 8192

typedef short v8s __attribute__((ext_vector_type(8)));
typedef float v4f __attribute__((ext_vector_type(4)));

__device__ __forceinline__ ushort f2bf(float f) {
    unsigned u = __float_as_uint(f);
    u += 0x7fffu + ((u >> 16) & 1u);   // RNE
    return (ushort)(u >> 16);
}
__device__ __forceinline__ float sigm(float x) { return 1.f / (1.f + __expf(-x)); }
__device__ __forceinline__ float tanh_f(float x) {
    x = fminf(15.f, fmaxf(-15.f, x));
    float e = __expf(2.f * x);
    return (e - 1.f) / (e + 1.f);
}
__device__ __forceinline__ void gload16(const void* g, void* l) {
    __builtin_amdgcn_global_load_lds(
        (const __attribute__((address_space(1))) void*)g,
        (__attribute__((address_space(3))) void*)l, 16, 0, 0);
}
// raw s_barrier has NO compiler memory semantics -> fence both sides
__device__ __forceinline__ void barrier_fenced() {
    __builtin_amdgcn_sched_barrier(0);
    asm volatile("" ::: "memory");
    __builtin_amdgcn_s_barrier();
    __builtin_amdgcn_sched_barrier(0);
    asm volatile("" ::: "memory");
}

// ------------------------------------------------- merged conversion kernel
__global__ __launch_bounds__(384) void convert_all(
    const float* __restrict__ Wxi, const float* __restrict__ Whi,
    const float* __restrict__ Wxf, const float* __restrict__ Whf,
    const float* __restrict__ Wxc, const float* __restrict__ Whc,
    const float* __restrict__ Wxo, const float* __restrict__ Who,
    const float* __restrict__ x,  const float* __restrict__ hs,
    const float* __restrict__ Why,
    ushort* __restrict__ Wcat, ushort* __restrict__ Xcat, ushort* __restrict__ WhyB)
{
    const int b = blockIdx.x;
    if (b < N1) {                       // Wcat[n][k], n = 4*h+g
        const int n = b, k = threadIdx.x * 8;
        const int h = n >> 2, g = n & 3;
        const float* src;
        if (k < I_) {
            const float* W = (g == 0) ? Wxi : (g == 1) ? Wxf : (g == 2) ? Wxc : Wxo;
            src = W + (size_t)h * I_ + k;
        } else {
            const float* W = (g == 0) ? Whi : (g == 1) ? Whf : (g == 2) ? Whc : Who;
            src = W + (size_t)h * H_ + (k - I_);
        }
        float4 a = *(const float4*)src;
        float4 c = *(const float4*)(src + 4);
        *(ushort4*)&Wcat[(size_t)n * K1 + k] =
            make_ushort4(f2bf(a.x), f2bf(a.y), f2bf(a.z), f2bf(a.w));
        *(ushort4*)&Wcat[(size_t)n * K1 + k + 4] =
            make_ushort4(f2bf(c.x), f2bf(c.y), f2bf(c.z), f2bf(c.w));
    } else if (b < N1 + B_) {           // Xcat[m][k] = [x | h]
        const int m = b - N1, k = threadIdx.x * 8;
        const float* src = (k < I_) ? (x + (size_t)m * I_ + k)
                                    : (hs + (size_t)m * H_ + (k - I_));
        float4 a = *(const float4*)src;
        float4 c = *(const float4*)(src + 4);
        *(ushort4*)&Xcat[(size_t)m * K1 + k] =
            make_ushort4(f2bf(a.x), f2bf(a.y), f2bf(a.z), f2bf(a.w));
        *(ushort4*)&Xcat[(size_t)m * K1 + k + 4] =
            make_ushort4(f2bf(c.x), f2bf(c.y), f2bf(c.z), f2bf(c.w));
    } else {                            // WhyB
        const int n = b - N1 - B_, k = threadIdx.x * 8;
        if (k < H_) {
            const float* src = Why + (size_t)n * H_ + k;
            float4 a = *(const float4*)src;
            float4 c = *(const float4*)(src + 4);
            *(ushort4*)&WhyB[(size_t)n * H_ + k] =
                make_ushort4(f2bf(a.x), f2bf(a.y), f2bf(a.z), f2bf(a.w));
            *(ushort4*)&WhyB[(size_t)n * H_ + k + 4] =
                make_ushort4(f2bf(c.x), f2bf(c.y), f2bf(c.z), f2bf(c.w));
        }
    }
}

// ---------------------------------------------------------------------------
// GEMM1: 256x256 tile, BK=32, 1024 threads (16 waves 4M x 4N, wave 64x64,
// acc[4][4]), DOUBLE-buffered 64KB LDS -> 2 blocks/CU = 32 waves/CU (full),
// counted vmcnt(2), fenced barriers (R12's proven loop pattern). Rationale:
// LDS-read bytes per MFMA drop 768->512B vs the 128^2 kernels (which measured
// ~88% of LDS BW); R14's only flaw was ring-3's 96KB killing 2-blocks/CU.
// Staging/swizzle/fragment algebra = R14 (HW-verified). Epilogue = R14's
// chunked scheme + R16's quad-transpose (HW-verified).
// ---------------------------------------------------------------------------

#define STAGE(D, TT) {                                                        \
    const int kb_ = (TT) * 32;                                                \
    ushort* l0_ = (ushort*)lds + (D) * 16384 + tid * 8;                       \
    gload16(aSrc + kb_, l0_);                                                 \
    gload16(bSrc + kb_, l0_ + 8192);                                          \
}

#define COMPUTE(D) {                                                          \
    const ushort* ba_ = (const ushort*)lds + (D) * 16384 + aRowU;             \
    const ushort* bb_ = (const ushort*)lds + (D) * 16384 + 8192 + bRowU;      \
    v8s af_[4], bf_[4];                                                       \
    _Pragma("unroll")                                                         \
    for (int mi = 0; mi < 4; ++mi)                                            \
        af_[mi] = *(const v8s*)&ba_[mi * 512 + colR];                         \
    _Pragma("unroll")                                                         \
    for (int ni = 0; ni < 4; ++ni)                                            \
        bf_[ni] = *(const v8s*)&bb_[ni * 512 + colR];                         \
    __builtin_amdgcn_s_setprio(1);                                            \
    _Pragma("unroll")                                                         \
    for (int mi = 0; mi < 4; ++mi)                                            \
      _Pragma("unroll")                                                       \
      for (int ni = 0; ni < 4; ++ni)                                          \
        acc[mi][ni] = __builtin_amdgcn_mfma_f32_16x16x32_bf16(                \
            af_[mi], bf_[ni], acc[mi][ni], 0, 0, 0);                          \
    __builtin_amdgcn_s_setprio(0);                                            \
}

__global__ __launch_bounds__(1024, 8) void gates_mm_256d2(
    const ushort* __restrict__ A, const ushort* __restrict__ Bm,
    const float* __restrict__ cs,
    const float* __restrict__ bxi, const float* __restrict__ bxf,
    const float* __restrict__ bxc, const float* __restrict__ bxo,
    float* __restrict__ hid_out, float* __restrict__ cell_out,
    ushort* __restrict__ hidB)
{
    __shared__ ushort lds[32768];   // 64 KB: buf d at d*16384 (A 16KB | B 16KB)

    const int tid  = threadIdx.x;
    const int lane = tid & 63;
    const int w    = tid >> 6;          // 0..15
    const int wm = w >> 2;              // 0..3  (64-row M slab)
    const int wn = w & 3;               // 0..3  (64-col N slab)

    const int blkN = blockIdx.x;        // 0..31 (fast: A-panel reuse)
    const int blkM = blockIdx.y;        // 0..15

    // staging (R14-verified): 256 rows x 32 cols, 64B rows = 4 slots of 16B;
    // dest linear tid*16B; source slot = (tid&3) ^ ((row>>1)&3), row = tid>>2
    const int srowS = tid >> 2;                        // 0..255
    const int colES = (((tid & 3) ^ ((tid >> 3) & 3)) << 3);
    const ushort* aSrc = A  + (size_t)(blkM * 256 + srowS) * K1 + colES;
    const ushort* bSrc = Bm + (size_t)(blkN * 256 + srowS) * K1 + colES;

    // fragment reads (R14-verified): slot = l4 ^ ((l15>>1)&3)
    const int l15 = lane & 15, l4 = lane >> 4;
    const int colR  = ((l4 ^ ((l15 >> 1) & 3)) << 3);
    const int aRowU = (wm * 64 + l15) * 32;
    const int bRowU = (wn * 64 + l15) * 32;

    v4f acc[4][4];
    #pragma unroll
    for (int mi = 0; mi < 4; ++mi)
      #pragma unroll
      for (int ni = 0; ni < 4; ++ni) acc[mi][ni] = (v4f)0.f;

    STAGE(0, 0)
    #pragma unroll 1
    for (int t = 0; t < 95; ++t) {
        STAGE((t + 1) & 1, t + 1)
        asm volatile("s_waitcnt vmcnt(2)" ::: "memory");
        barrier_fenced();                 // buf t&1 writes landed for all waves
        COMPUTE(t & 1)
        barrier_fenced();                 // reads done before next overwrite
    }
    asm volatile("s_waitcnt vmcnt(0)" ::: "memory");
    barrier_fenced();
    COMPUTE(1)                            // t = 95
    barrier_fenced();                     // all reads done before LDS repurpose

    // ========= fused LSTM epilogue: 4 chunks of 64 rows, quad-transpose ======
    // csT/cT/hT [64][66] f32, hbT [64][68] bf16 = 59.4 KB (fits 64KB)
    float*  csT = (float*)lds;             // floats 0..4223
    float*  cT  = (float*)lds + 4224;
    float*  hT  = (float*)lds + 8448;
    ushort* hbT = (ushort*)lds + 25344;

    const int g = lane & 3;
    const int Mb = blkM * 256;
    const int hbase = blkN * 64;

    int hl[4]; float biasj[4];
    #pragma unroll
    for (int ni = 0; ni < 4; ++ni) {
        hl[ni] = wn * 16 + ni * 4 + (l15 >> 2);     // 0..63 (quad-uniform)
        const float* bp = (g == 0) ? bxi : (g == 1) ? bxf : (g == 2) ? bxc : bxo;
        biasj[ni] = bp[hbase + hl[ni]];
    }

    const int erow = tid >> 4;           // 0..63
    const int ecol = (tid & 15) * 4;     // 0..60

    #pragma unroll 1
    for (int c = 0; c < 4; ++c) {
        __syncthreads();
        // coop-load cs chunk [64][64] coalesced (1 float4/thread)
        *(float4*)&csT[erow * 66 + ecol] =
            *(const float4*)(cs + (size_t)(Mb + c * 64 + erow) * H_ + hbase + ecol);
        __syncthreads();
        if (wm == c) {
            #pragma unroll
            for (int mi = 0; mi < 4; ++mi) {
              #pragma unroll
              for (int ni = 0; ni < 4; ++ni) {
                float v0 = acc[mi][ni][0] + biasj[ni];
                float v1 = acc[mi][ni][1] + biasj[ni];
                float v2 = acc[mi][ni][2] + biasj[ni];
                float v3 = acc[mi][ni][3] + biasj[ni];
                {   // quad 4x4 transpose (R16-verified): new(l,r) = old(r,l)
                    float xx, yy;
                    xx = (g & 1) ? v0 : v1; yy = __shfl_xor(xx, 1, 64);
                    if (g & 1) v0 = yy; else v1 = yy;
                    xx = (g & 1) ? v2 : v3; yy = __shfl_xor(xx, 1, 64);
                    if (g & 1) v2 = yy; else v3 = yy;
                    xx = (g & 2) ? v0 : v2; yy = __shfl_xor(xx, 2, 64);
                    if (g & 2) v0 = yy; else v2 = yy;
                    xx = (g & 2) ? v1 : v3; yy = __shfl_xor(xx, 2, 64);
                    if (g & 2) v1 = yy; else v3 = yy;
                }
                const int ml = mi * 16 + l4 * 4 + g;   // 0..63 chunk-local row
                const float Ig = sigm(v0), Fg = sigm(v1);
                const float Cg = tanh_f(v2), Og = sigm(v3);
                const float c_old = csT[ml * 66 + hl[ni]];
                const float c_new = Fg * c_old + Ig * Cg;
                const float h_new = Og * tanh_f(c_new);
                cT [ml * 66 + hl[ni]] = c_new;
                hT [ml * 66 + hl[ni]] = h_new;
                hbT[ml * 68 + hl[ni]] = f2bf(h_new);
              }
            }
        }
        __syncthreads();
        // coop-store coalesced
        {
            const size_t gof = (size_t)(Mb + c * 64 + erow) * H_ + hbase + ecol;
            *(float4*)&cell_out[gof] = *(const float4*)&cT[erow * 66 + ecol];
            *(float4*)&hid_out [gof] = *(const float4*)&hT[erow * 66 + ecol];
            *(uint2*)&hidB[gof]      = *(const uint2*)&hbT[erow * 68 + ecol];
        }
    }
}

// ---------------------------------------------------------------------------
// GEMM2: out = hidB @ WhyB^T + b — R12 loop structure
// (128x128, BK=64, 512 threads / 8 waves, dbuf 64KB, vmcnt(4), fenced).
// ---------------------------------------------------------------------------

#define COMPUTE2(D) {                                                         \
    const ushort* ba_ = (const ushort*)lds + (D) * 16384 + aRowU;             \
    const ushort* bb_ = (const ushort*)lds + (D) * 16384 + 8192 + bRowU;      \
    v8s af_[4][2], bf_[2][2];                                                 \
    _Pragma("unroll")                                                         \
    for (int mi = 0; mi < 4; ++mi) {                                          \
        af_[mi][0] = *(const v8s*)&ba_[mi * 1024 + col0];                     \
        af_[mi][1] = *(const v8s*)&ba_[mi * 1024 + col1];                     \
    }                                                                         \
    _Pragma("unroll")                                                         \
    for (int ni = 0; ni < 2; ++ni) {                                          \
        bf_[ni][0] = *(const v8s*)&bb_[ni * 1024 + col0];                     \
        bf_[ni][1] = *(const v8s*)&bb_[ni * 1024 + col1];                     \
    }                                                                         \
    __builtin_amdgcn_s_setprio(1);                                            \
    _Pragma("unroll")                                                         \
    for (int mi = 0; mi < 4; ++mi)                                            \
      _Pragma("unroll")                                                       \
      for (int ni = 0; ni < 2; ++ni) {                                        \
        acc[mi][ni] = __builtin_amdgcn_mfma_f32_16x16x32_bf16(                \
            af_[mi][0], bf_[ni][0], acc[mi][ni], 0, 0, 0);                    \
        acc[mi][ni] = __builtin_amdgcn_mfma_f32_16x16x32_bf16(                \
            af_[mi][1], bf_[ni][1], acc[mi][ni], 0, 0, 0);                    \
      }                                                                       \
    __builtin_amdgcn_s_setprio(0);                                            \
}

#define STAGE2(D, TT) {                                                       \
    const int kb_ = (TT) * 64;                                                \
    ushort* l0_ = (ushort*)lds + (D) * 16384 + tid * 8;                       \
    gload16(aSrc + kb_,             l0_);                                     \
    gload16(aSrc + 64 * H_ + kb_,   l0_ + 4096);                              \
    gload16(bSrc + kb_,             l0_ + 8192);                              \
    gload16(bSrc + 64 * H_ + kb_,   l0_ + 12288);                             \
}

__global__ __launch_bounds__(512, 4) void out_mm_bf16(
    const ushort* __restrict__ A, const ushort* __restrict__ Bm,
    const float* __restrict__ bw, float* __restrict__ out)
{
    __shared__ ushort lds[32768];

    const int tid  = threadIdx.x;
    const int lane = tid & 63;
    const int w    = tid >> 6;
    const int wm = w >> 2;              // 0..1
    const int wn = w & 3;               // 0..3

    const int blkN = blockIdx.x;        // 0..7
    const int blkM = blockIdx.y;        // 0..31

    const int srowS = tid >> 3;
    const int colES = (((tid & 7) ^ (srowS & 7)) << 3);
    const ushort* aSrc = A  + (size_t)(blkM * 128 + srowS) * H_ + colES;
    const ushort* bSrc = Bm + (size_t)(blkN * 128 + srowS) * H_ + colES;

    const int l15 = lane & 15, l4 = lane >> 4;
    const int fx = l15 & 7;
    const int col0 = ((l4      ^ fx) << 3);
    const int col1 = (((4 + l4) ^ fx) << 3);
    const int aRowU = (wm * 64 + l15) * 64;
    const int bRowU = (wn * 32 + l15) * 64;

    v4f acc[4][2];
    #pragma unroll
    for (int mi = 0; mi < 4; ++mi)
      #pragma unroll
      for (int ni = 0; ni < 2; ++ni) acc[mi][ni] = (v4f)0.f;

    STAGE2(0, 0)
    #pragma unroll 1
    for (int t = 0; t < 31; ++t) {
        STAGE2((t + 1) & 1, t + 1)
        asm volatile("s_waitcnt vmcnt(4)" ::: "memory");
        barrier_fenced();
        COMPUTE2(t & 1)
        barrier_fenced();
    }
    asm volatile("s_waitcnt vmcnt(0)" ::: "memory");
    barrier_fenced();
    COMPUTE2(1)

    // epilogue: bias + direct store
    #pragma unroll
    for (int mi = 0; mi < 4; ++mi) {
      #pragma unroll
      for (int r = 0; r < 4; ++r) {
        const int m = blkM * 128 + wm * 64 + mi * 16 + l4 * 4 + r;
        #pragma unroll
        for (int ni = 0; ni < 2; ++ni) {
            const int n = blkN * 128 + wn * 32 + ni * 16 + l15;
            out[(size_t)m * O_ + n] = acc[mi][ni][r] + bw[n];
        }
      }
    }
}

extern "C" void kernel_launch(void* const* d_in, const int* in_sizes, int n_in,
                              void* d_out, int out_size, void* d_ws, size_t ws_size,
                              hipStream_t stream) {
    const float* x   = (const float*)d_in[0];
    const float* hs  = (const float*)d_in[1];
    const float* cs  = (const float*)d_in[2];
    const float* Wxi = (const float*)d_in[3];
    const float* bxi = (const float*)d_in[4];
    const float* Whi = (const float*)d_in[5];
    const float* Wxf = (const float*)d_in[6];
    const float* bxf = (const float*)d_in[7];
    const float* Whf = (const float*)d_in[8];
    const float* Wxc = (const float*)d_in[9];
    const float* bxc = (const float*)d_in[10];
    const float* Whc = (const float*)d_in[11];
    const float* Wxo = (const float*)d_in[12];
    const float* bxo = (const float*)d_in[13];
    const float* Who = (const float*)d_in[14];
    const float* Why = (const float*)d_in[15];
    const float* bwy = (const float*)d_in[16];

    float* out      = (float*)d_out;
    float* hid_out  = out + (size_t)B_ * O_;
    float* cell_out = hid_out + (size_t)B_ * H_;

    const size_t szW = (size_t)N1 * K1;
    const size_t szX = (size_t)B_ * K1;
    const size_t szY = (size_t)O_ * H_;

    ushort* Wcat = (ushort*)d_ws;
    ushort* Xcat = Wcat + szW;
    ushort* WhyB = Xcat + szX;
    ushort* HidB = WhyB + szY;

    convert_all<<<dim3(N1 + B_ + O_), 384, 0, stream>>>(
        Wxi, Whi, Wxf, Whf, Wxc, Whc, Wxo, Who, x, hs, Why, Wcat, Xcat, WhyB);

    gates_mm_256d2<<<dim3(N1 / 256, B_ / 256), 1024, 0, stream>>>(
        Xcat, Wcat, cs, bxi, bxf, bxc, bxo, hid_out, cell_out, HidB);
    out_mm_bf16<<<dim3(O_ / 128, B_ / 128), 512, 0, stream>>>(
        HidB, WhyB, bwy, out);
}

// Round 18
// 289.314 us; speedup vs baseline: 10.3567x; 10.3567x over previous
//
#include <hip/hip_runtime.h>
#include <hip/hip_bf16.h>

#define B_ 4096
#define I_ 1024
#define H_ 2048
#define O_ 1024
#define K1 (I_ + H_)   // 3072
#define N1 (4 * H_)    // 8192

typedef short v8s __attribute__((ext_vector_type(8)));
typedef float v4f __attribute__((ext_vector_type(4)));

__device__ __forceinline__ ushort f2bf(float f) {
    unsigned u = __float_as_uint(f);
    u += 0x7fffu + ((u >> 16) & 1u);   // RNE
    return (ushort)(u >> 16);
}
__device__ __forceinline__ float sigm(float x) { return 1.f / (1.f + __expf(-x)); }
__device__ __forceinline__ float tanh_f(float x) {
    x = fminf(15.f, fmaxf(-15.f, x));
    float e = __expf(2.f * x);
    return (e - 1.f) / (e + 1.f);
}
__device__ __forceinline__ void gload16(const void* g, void* l) {
    __builtin_amdgcn_global_load_lds(
        (const __attribute__((address_space(1))) void*)g,
        (__attribute__((address_space(3))) void*)l, 16, 0, 0);
}
// raw s_barrier has NO compiler memory semantics -> fence both sides
__device__ __forceinline__ void barrier_fenced() {
    __builtin_amdgcn_sched_barrier(0);
    asm volatile("" ::: "memory");
    __builtin_amdgcn_s_barrier();
    __builtin_amdgcn_sched_barrier(0);
    asm volatile("" ::: "memory");
}

// ------------------------------------------------- merged conversion kernel
__global__ __launch_bounds__(384) void convert_all(
    const float* __restrict__ Wxi, const float* __restrict__ Whi,
    const float* __restrict__ Wxf, const float* __restrict__ Whf,
    const float* __restrict__ Wxc, const float* __restrict__ Whc,
    const float* __restrict__ Wxo, const float* __restrict__ Who,
    const float* __restrict__ x,  const float* __restrict__ hs,
    const float* __restrict__ Why,
    ushort* __restrict__ Wcat, ushort* __restrict__ Xcat, ushort* __restrict__ WhyB)
{
    const int b = blockIdx.x;
    if (b < N1) {                       // Wcat[n][k], n = 4*h+g
        const int n = b, k = threadIdx.x * 8;
        const int h = n >> 2, g = n & 3;
        const float* src;
        if (k < I_) {
            const float* W = (g == 0) ? Wxi : (g == 1) ? Wxf : (g == 2) ? Wxc : Wxo;
            src = W + (size_t)h * I_ + k;
        } else {
            const float* W = (g == 0) ? Whi : (g == 1) ? Whf : (g == 2) ? Whc : Who;
            src = W + (size_t)h * H_ + (k - I_);
        }
        float4 a = *(const float4*)src;
        float4 c = *(const float4*)(src + 4);
        *(ushort4*)&Wcat[(size_t)n * K1 + k] =
            make_ushort4(f2bf(a.x), f2bf(a.y), f2bf(a.z), f2bf(a.w));
        *(ushort4*)&Wcat[(size_t)n * K1 + k + 4] =
            make_ushort4(f2bf(c.x), f2bf(c.y), f2bf(c.z), f2bf(c.w));
    } else if (b < N1 + B_) {           // Xcat[m][k] = [x | h]
        const int m = b - N1, k = threadIdx.x * 8;
        const float* src = (k < I_) ? (x + (size_t)m * I_ + k)
                                    : (hs + (size_t)m * H_ + (k - I_));
        float4 a = *(const float4*)src;
        float4 c = *(const float4*)(src + 4);
        *(ushort4*)&Xcat[(size_t)m * K1 + k] =
            make_ushort4(f2bf(a.x), f2bf(a.y), f2bf(a.z), f2bf(a.w));
        *(ushort4*)&Xcat[(size_t)m * K1 + k + 4] =
            make_ushort4(f2bf(c.x), f2bf(c.y), f2bf(c.z), f2bf(c.w));
    } else {                            // WhyB
        const int n = b - N1 - B_, k = threadIdx.x * 8;
        if (k < H_) {
            const float* src = Why + (size_t)n * H_ + k;
            float4 a = *(const float4*)src;
            float4 c = *(const float4*)(src + 4);
            *(ushort4*)&WhyB[(size_t)n * H_ + k] =
                make_ushort4(f2bf(a.x), f2bf(a.y), f2bf(a.z), f2bf(a.w));
            *(ushort4*)&WhyB[(size_t)n * H_ + k + 4] =
                make_ushort4(f2bf(c.x), f2bf(c.y), f2bf(c.z), f2bf(c.w));
        }
    }
}

// ---------------------------------------------------------------------------
// GEMM1: 256M x 128N block, BK=32, 512 threads (8 waves 4M x 2N, wave tile
// 64x64, acc[4][4] -> 512 B LDS-read per MFMA, vs 768 in the 128^2 shape).
// RING-3 LDS (3 x 24KB = 72KB -> 2 blocks/CU = 16 waves/CU), ONE fenced
// barrier per K-step (96 total), counted vmcnt(3) (3 loads/stage, 1-tile
// slack). All algebra HW-verified: staging/fragment maps = R11 (passed,
// 64 VGPR), ring-3 loop = R13 (passed), transpose epilogue = R16 (passed).
// ---------------------------------------------------------------------------

#define STAGE(BUF, TT) {                                                      \
    const int kb_ = (TT) * 32;                                                \
    ushort* l0_ = (ushort*)lds + (BUF) * 12288 + tid * 8;                     \
    gload16(aSrc + kb_,              l0_);                                    \
    gload16(aSrc + 128 * K1 + kb_,   l0_ + 4096);                             \
    gload16(bSrc + kb_,              l0_ + 8192);                             \
}

#define COMPUTE(BUF) {                                                        \
    const ushort* ba_ = (const ushort*)lds + (BUF) * 12288 + aRowU;           \
    const ushort* bb_ = (const ushort*)lds + (BUF) * 12288 + 8192 + bRowU;    \
    v8s af_[4], bf_[4];                                                       \
    _Pragma("unroll")                                                         \
    for (int mi = 0; mi < 4; ++mi)                                            \
        af_[mi] = *(const v8s*)&ba_[mi * 512 + colR];                         \
    _Pragma("unroll")                                                         \
    for (int ni = 0; ni < 4; ++ni)                                            \
        bf_[ni] = *(const v8s*)&bb_[ni * 512 + colR];                         \
    __builtin_amdgcn_s_setprio(1);                                            \
    _Pragma("unroll")                                                         \
    for (int mi = 0; mi < 4; ++mi)                                            \
      _Pragma("unroll")                                                       \
      for (int ni = 0; ni < 4; ++ni)                                          \
        acc[mi][ni] = __builtin_amdgcn_mfma_f32_16x16x32_bf16(                \
            af_[mi], bf_[ni], acc[mi][ni], 0, 0, 0);                          \
    __builtin_amdgcn_s_setprio(0);                                            \
}

__global__ __launch_bounds__(512, 4) void gates_mm_256x128r3(
    const ushort* __restrict__ A, const ushort* __restrict__ Bm,
    const float* __restrict__ cs,
    const float* __restrict__ bxi, const float* __restrict__ bxf,
    const float* __restrict__ bxc, const float* __restrict__ bxo,
    float* __restrict__ hid_out, float* __restrict__ cell_out,
    ushort* __restrict__ hidB)
{
    __shared__ ushort lds[36864];   // 72 KB: buf k at k*12288 (A 16KB | B 8KB)

    const int tid  = threadIdx.x;
    const int lane = tid & 63;
    const int w    = tid >> 6;          // 0..7
    const int wm = w >> 1;              // 0..3  (64-row M slab)
    const int wn = w & 1;               // 0..1  (64-col N half)

    const int blkN = blockIdx.x;        // 0..63 (fast: A-panel reuse)
    const int blkM = blockIdx.y;        // 0..15

    // staging (R11-verified): 64B rows = 4 slots of 16B; dest linear tid*16B;
    // source slot = (tid&3) ^ ((row>>1)&3), row = tid>>2 (0..127)
    const int srowS = tid >> 2;
    const int colES = (((tid & 3) ^ ((tid >> 3) & 3)) << 3);
    const ushort* aSrc = A  + (size_t)(blkM * 256 + srowS) * K1 + colES;
    const ushort* bSrc = Bm + (size_t)(blkN * 128 + srowS) * K1 + colES;

    // fragment reads (R11-verified): slot = l4 ^ ((l15>>1)&3)
    const int l15 = lane & 15, l4 = lane >> 4;
    const int colR  = ((l4 ^ ((l15 >> 1) & 3)) << 3);
    const int aRowU = (wm * 64 + l15) * 32;
    const int bRowU = (wn * 64 + l15) * 32;

    v4f acc[4][4];
    #pragma unroll
    for (int mi = 0; mi < 4; ++mi)
      #pragma unroll
      for (int ni = 0; ni < 4; ++ni) acc[mi][ni] = (v4f)0.f;

    // prologue: tiles 0,1 into bufs 0,1 (6 loads in flight)
    STAGE(0, 0)
    STAGE(1, 1)

    // main: 1 barrier per K-step; STAGE(t+2) overwrites the buffer whose
    // readers (COMPUTE(t-1)) finished before this step's barrier.
    #pragma unroll 3
    for (int t = 0; t < 94; ++t) {
        asm volatile("s_waitcnt vmcnt(3)" ::: "memory");   // tile t landed
        barrier_fenced();
        COMPUTE(t % 3)
        STAGE((t + 2) % 3, t + 2)
    }
    // t = 94: no stage (tile 96 doesn't exist)
    asm volatile("s_waitcnt vmcnt(3)" ::: "memory");
    barrier_fenced();
    COMPUTE(94 % 3)
    // t = 95: drain fully
    asm volatile("s_waitcnt vmcnt(0)" ::: "memory");
    barrier_fenced();
    COMPUTE(95 % 3)
    barrier_fenced();                    // all reads done before LDS repurpose

    // ==== fused LSTM epilogue: 4 chunks of 64 rows (wm==c), quad-transpose ===
    // csT/cT/hT [64][34] f32, hbT [64][36] bf16 = 30.7 KB (fits 72KB)
    float*  csT = (float*)lds;             // floats 0..2175
    float*  cT  = (float*)lds + 2176;
    float*  hT  = (float*)lds + 4352;
    ushort* hbT = (ushort*)lds + 13056;

    const int g = lane & 3;
    const int Mb = blkM * 256;
    const int hbase = blkN * 32;

    int hl[4]; float biasj[4];
    #pragma unroll
    for (int ni = 0; ni < 4; ++ni) {
        hl[ni] = wn * 16 + ni * 4 + (l15 >> 2);     // 0..31 (quad-uniform)
        const float* bp = (g == 0) ? bxi : (g == 1) ? bxf : (g == 2) ? bxc : bxo;
        biasj[ni] = bp[hbase + hl[ni]];
    }

    const int erow = tid >> 3;           // 0..63
    const int ecol = (tid & 7) * 4;      // 0..28

    #pragma unroll 1
    for (int c = 0; c < 4; ++c) {
        __syncthreads();
        // coop-load cs chunk [64][32] coalesced (1 float4/thread)
        *(float4*)&csT[erow * 34 + ecol] =
            *(const float4*)(cs + (size_t)(Mb + c * 64 + erow) * H_ + hbase + ecol);
        __syncthreads();
        if (wm == c) {
            #pragma unroll
            for (int mi = 0; mi < 4; ++mi) {
              #pragma unroll
              for (int ni = 0; ni < 4; ++ni) {
                float v0 = acc[mi][ni][0] + biasj[ni];
                float v1 = acc[mi][ni][1] + biasj[ni];
                float v2 = acc[mi][ni][2] + biasj[ni];
                float v3 = acc[mi][ni][3] + biasj[ni];
                {   // quad 4x4 transpose (R16-verified): new(l,r) = old(r,l)
                    float xx, yy;
                    xx = (g & 1) ? v0 : v1; yy = __shfl_xor(xx, 1, 64);
                    if (g & 1) v0 = yy; else v1 = yy;
                    xx = (g & 1) ? v2 : v3; yy = __shfl_xor(xx, 1, 64);
                    if (g & 1) v2 = yy; else v3 = yy;
                    xx = (g & 2) ? v0 : v2; yy = __shfl_xor(xx, 2, 64);
                    if (g & 2) v0 = yy; else v2 = yy;
                    xx = (g & 2) ? v1 : v3; yy = __shfl_xor(xx, 2, 64);
                    if (g & 2) v1 = yy; else v3 = yy;
                }
                const int ml = mi * 16 + l4 * 4 + g;   // 0..63 chunk-local row
                const float Ig = sigm(v0), Fg = sigm(v1);
                const float Cg = tanh_f(v2), Og = sigm(v3);
                const float c_old = csT[ml * 34 + hl[ni]];
                const float c_new = Fg * c_old + Ig * Cg;
                const float h_new = Og * tanh_f(c_new);
                cT [ml * 34 + hl[ni]] = c_new;
                hT [ml * 34 + hl[ni]] = h_new;
                hbT[ml * 36 + hl[ni]] = f2bf(h_new);
              }
            }
        }
        __syncthreads();
        // coop-store coalesced
        {
            const size_t gof = (size_t)(Mb + c * 64 + erow) * H_ + hbase + ecol;
            *(float4*)&cell_out[gof] = *(const float4*)&cT[erow * 34 + ecol];
            *(float4*)&hid_out [gof] = *(const float4*)&hT[erow * 34 + ecol];
            *(uint2*)&hidB[gof]      = *(const uint2*)&hbT[erow * 36 + ecol];
        }
    }
}

// ---------------------------------------------------------------------------
// GEMM2: out = hidB @ WhyB^T + b — R12 loop structure (unchanged from R16)
// ---------------------------------------------------------------------------

#define COMPUTE2(D) {                                                         \
    const ushort* ba_ = (const ushort*)lds + (D) * 16384 + aRowU;             \
    const ushort* bb_ = (const ushort*)lds + (D) * 16384 + 8192 + bRowU;      \
    v8s af_[4][2], bf_[2][2];                                                 \
    _Pragma("unroll")                                                         \
    for (int mi = 0; mi < 4; ++mi) {                                          \
        af_[mi][0] = *(const v8s*)&ba_[mi * 1024 + col0];                     \
        af_[mi][1] = *(const v8s*)&ba_[mi * 1024 + col1];                     \
    }                                                                         \
    _Pragma("unroll")                                                         \
    for (int ni = 0; ni < 2; ++ni) {                                          \
        bf_[ni][0] = *(const v8s*)&bb_[ni * 1024 + col0];                     \
        bf_[ni][1] = *(const v8s*)&bb_[ni * 1024 + col1];                     \
    }                                                                         \
    __builtin_amdgcn_s_setprio(1);                                            \
    _Pragma("unroll")                                                         \
    for (int mi = 0; mi < 4; ++mi)                                            \
      _Pragma("unroll")                                                       \
      for (int ni = 0; ni < 2; ++ni) {                                        \
        acc[mi][ni] = __builtin_amdgcn_mfma_f32_16x16x32_bf16(                \
            af_[mi][0], bf_[ni][0], acc[mi][ni], 0, 0, 0);                    \
        acc[mi][ni] = __builtin_amdgcn_mfma_f32_16x16x32_bf16(                \
            af_[mi][1], bf_[ni][1], acc[mi][ni], 0, 0, 0);                    \
      }                                                                       \
    __builtin_amdgcn_s_setprio(0);                                            \
}

#define STAGE2(D, TT) {                                                       \
    const int kb_ = (TT) * 64;                                                \
    ushort* l0_ = (ushort*)lds + (D) * 16384 + tid * 8;                       \
    gload16(aSrc + kb_,             l0_);                                     \
    gload16(aSrc + 64 * H_ + kb_,   l0_ + 4096);                              \
    gload16(bSrc + kb_,             l0_ + 8192);                              \
    gload16(bSrc + 64 * H_ + kb_,   l0_ + 12288);                             \
}

__global__ __launch_bounds__(512, 4) void out_mm_bf16(
    const ushort* __restrict__ A, const ushort* __restrict__ Bm,
    const float* __restrict__ bw, float* __restrict__ out)
{
    __shared__ ushort lds[32768];

    const int tid  = threadIdx.x;
    const int lane = tid & 63;
    const int w    = tid >> 6;
    const int wm = w >> 2;              // 0..1
    const int wn = w & 3;               // 0..3

    const int blkN = blockIdx.x;        // 0..7
    const int blkM = blockIdx.y;        // 0..31

    const int srowS = tid >> 3;
    const int colES = (((tid & 7) ^ (srowS & 7)) << 3);
    const ushort* aSrc = A  + (size_t)(blkM * 128 + srowS) * H_ + colES;
    const ushort* bSrc = Bm + (size_t)(blkN * 128 + srowS) * H_ + colES;

    const int l15 = lane & 15, l4 = lane >> 4;
    const int fx = l15 & 7;
    const int col0 = ((l4      ^ fx) << 3);
    const int col1 = (((4 + l4) ^ fx) << 3);
    const int aRowU = (wm * 64 + l15) * 64;
    const int bRowU = (wn * 32 + l15) * 64;

    v4f acc[4][2];
    #pragma unroll
    for (int mi = 0; mi < 4; ++mi)
      #pragma unroll
      for (int ni = 0; ni < 2; ++ni) acc[mi][ni] = (v4f)0.f;

    STAGE2(0, 0)
    #pragma unroll 1
    for (int t = 0; t < 31; ++t) {
        STAGE2((t + 1) & 1, t + 1)
        asm volatile("s_waitcnt vmcnt(4)" ::: "memory");
        barrier_fenced();
        COMPUTE2(t & 1)
        barrier_fenced();
    }
    asm volatile("s_waitcnt vmcnt(0)" ::: "memory");
    barrier_fenced();
    COMPUTE2(1)

    // epilogue: bias + direct store
    #pragma unroll
    for (int mi = 0; mi < 4; ++mi) {
      #pragma unroll
      for (int r = 0; r < 4; ++r) {
        const int m = blkM * 128 + wm * 64 + mi * 16 + l4 * 4 + r;
        #pragma unroll
        for (int ni = 0; ni < 2; ++ni) {
            const int n = blkN * 128 + wn * 32 + ni * 16 + l15;
            out[(size_t)m * O_ + n] = acc[mi][ni][r] + bw[n];
        }
      }
    }
}

extern "C" void kernel_launch(void* const* d_in, const int* in_sizes, int n_in,
                              void* d_out, int out_size, void* d_ws, size_t ws_size,
                              hipStream_t stream) {
    const float* x   = (const float*)d_in[0];
    const float* hs  = (const float*)d_in[1];
    const float* cs  = (const float*)d_in[2];
    const float* Wxi = (const float*)d_in[3];
    const float* bxi = (const float*)d_in[4];
    const float* Whi = (const float*)d_in[5];
    const float* Wxf = (const float*)d_in[6];
    const float* bxf = (const float*)d_in[7];
    const float* Whf = (const float*)d_in[8];
    const float* Wxc = (const float*)d_in[9];
    const float* bxc = (const float*)d_in[10];
    const float* Whc = (const float*)d_in[11];
    const float* Wxo = (const float*)d_in[12];
    const float* bxo = (const float*)d_in[13];
    const float* Who = (const float*)d_in[14];
    const float* Why = (const float*)d_in[15];
    const float* bwy = (const float*)d_in[16];

    float* out      = (float*)d_out;
    float* hid_out  = out + (size_t)B_ * O_;
    float* cell_out = hid_out + (size_t)B_ * H_;

    const size_t szW = (size_t)N1 * K1;
    const size_t szX = (size_t)B_ * K1;
    const size_t szY = (size_t)O_ * H_;

    ushort* Wcat = (ushort*)d_ws;
    ushort* Xcat = Wcat + szW;
    ushort* WhyB = Xcat + szX;
    ushort* HidB = WhyB + szY;

    convert_all<<<dim3(N1 + B_ + O_), 384, 0, stream>>>(
        Wxi, Whi, Wxf, Whf, Wxc, Whc, Wxo, Who, x, hs, Why, Wcat, Xcat, WhyB);

    gates_mm_256x128r3<<<dim3(N1 / 128, B_ / 256), 512, 0, stream>>>(
        Xcat, Wcat, cs, bxi, bxf, bxc, bxo, hid_out, cell_out, HidB);
    out_mm_bf16<<<dim3(O_ / 128, B_ / 128), 512, 0, stream>>>(
        HidB, WhyB, bwy, out);
}

// Round 19
// 281.526 us; speedup vs baseline: 10.6432x; 1.0277x over previous
//
#include <hip/hip_runtime.h>
#include <hip/hip_bf16.h>

#define B_ 4096
#define I_ 1024
#define H_ 2048
#define O_ 1024
#define K1 (I_ + H_)   // 3072
#define N1 (4 * H_)    // 8192

typedef short v8s __attribute__((ext_vector_type(8)));
typedef float v4f __attribute__((ext_vector_type(4)));

__device__ __forceinline__ ushort f2bf(float f) {
    unsigned u = __float_as_uint(f);
    u += 0x7fffu + ((u >> 16) & 1u);   // RNE
    return (ushort)(u >> 16);
}
__device__ __forceinline__ float sigm(float x) { return 1.f / (1.f + __expf(-x)); }
__device__ __forceinline__ float tanh_f(float x) {
    x = fminf(15.f, fmaxf(-15.f, x));
    float e = __expf(2.f * x);
    return (e - 1.f) / (e + 1.f);
}
__device__ __forceinline__ void gload16(const void* g, void* l) {
    __builtin_amdgcn_global_load_lds(
        (const __attribute__((address_space(1))) void*)g,
        (__attribute__((address_space(3))) void*)l, 16, 0, 0);
}
// raw s_barrier has NO compiler memory semantics -> fence both sides
__device__ __forceinline__ void barrier_fenced() {
    __builtin_amdgcn_sched_barrier(0);
    asm volatile("" ::: "memory");
    __builtin_amdgcn_s_barrier();
    __builtin_amdgcn_sched_barrier(0);
    asm volatile("" ::: "memory");
}

// ------------------------------------------------- merged conversion kernel
__global__ __launch_bounds__(384) void convert_all(
    const float* __restrict__ Wxi, const float* __restrict__ Whi,
    const float* __restrict__ Wxf, const float* __restrict__ Whf,
    const float* __restrict__ Wxc, const float* __restrict__ Whc,
    const float* __restrict__ Wxo, const float* __restrict__ Who,
    const float* __restrict__ x,  const float* __restrict__ hs,
    const float* __restrict__ Why,
    ushort* __restrict__ Wcat, ushort* __restrict__ Xcat, ushort* __restrict__ WhyB)
{
    const int b = blockIdx.x;
    if (b < N1) {                       // Wcat[n][k], n = 4*h+g
        const int n = b, k = threadIdx.x * 8;
        const int h = n >> 2, g = n & 3;
        const float* src;
        if (k < I_) {
            const float* W = (g == 0) ? Wxi : (g == 1) ? Wxf : (g == 2) ? Wxc : Wxo;
            src = W + (size_t)h * I_ + k;
        } else {
            const float* W = (g == 0) ? Whi : (g == 1) ? Whf : (g == 2) ? Whc : Who;
            src = W + (size_t)h * H_ + (k - I_);
        }
        float4 a = *(const float4*)src;
        float4 c = *(const float4*)(src + 4);
        *(ushort4*)&Wcat[(size_t)n * K1 + k] =
            make_ushort4(f2bf(a.x), f2bf(a.y), f2bf(a.z), f2bf(a.w));
        *(ushort4*)&Wcat[(size_t)n * K1 + k + 4] =
            make_ushort4(f2bf(c.x), f2bf(c.y), f2bf(c.z), f2bf(c.w));
    } else if (b < N1 + B_) {           // Xcat[m][k] = [x | h]
        const int m = b - N1, k = threadIdx.x * 8;
        const float* src = (k < I_) ? (x + (size_t)m * I_ + k)
                                    : (hs + (size_t)m * H_ + (k - I_));
        float4 a = *(const float4*)src;
        float4 c = *(const float4*)(src + 4);
        *(ushort4*)&Xcat[(size_t)m * K1 + k] =
            make_ushort4(f2bf(a.x), f2bf(a.y), f2bf(a.z), f2bf(a.w));
        *(ushort4*)&Xcat[(size_t)m * K1 + k + 4] =
            make_ushort4(f2bf(c.x), f2bf(c.y), f2bf(c.z), f2bf(c.w));
    } else {                            // WhyB
        const int n = b - N1 - B_, k = threadIdx.x * 8;
        if (k < H_) {
            const float* src = Why + (size_t)n * H_ + k;
            float4 a = *(const float4*)src;
            float4 c = *(const float4*)(src + 4);
            *(ushort4*)&WhyB[(size_t)n * H_ + k] =
                make_ushort4(f2bf(a.x), f2bf(a.y), f2bf(a.z), f2bf(a.w));
            *(ushort4*)&WhyB[(size_t)n * H_ + k + 4] =
                make_ushort4(f2bf(c.x), f2bf(c.y), f2bf(c.z), f2bf(c.w));
        }
    }
}

// ---------------------------------------------------------------------------
// GEMM1 (best measured, R16): 128x128 tile, BK=64, 8 waves (2M x 4N,
// acc[4][2]), dbuf 64KB LDS -> 2 blocks/CU, counted vmcnt(4), fenced
// barriers, slot^(row&7) swizzle both sides, setprio around MFMA.
// Epilogue: quad 4x4 transpose -> each lane computes one full LSTM cell.
// ---------------------------------------------------------------------------

#define STAGE(D, TT) {                                                        \
    const int kb_ = (TT) * 64;                                                \
    ushort* l0_ = (ushort*)lds + (D) * 16384 + tid * 8;                       \
    gload16(aSrc + kb_,             l0_);                                     \
    gload16(aSrc + 64 * K1 + kb_,   l0_ + 4096);                              \
    gload16(bSrc + kb_,             l0_ + 8192);                              \
    gload16(bSrc + 64 * K1 + kb_,   l0_ + 12288);                             \
}

#define COMPUTE(D) {                                                          \
    const ushort* ba_ = (const ushort*)lds + (D) * 16384 + aRowU;             \
    const ushort* bb_ = (const ushort*)lds + (D) * 16384 + 8192 + bRowU;      \
    v8s af_[4][2], bf_[2][2];                                                 \
    _Pragma("unroll")                                                         \
    for (int mi = 0; mi < 4; ++mi) {                                          \
        af_[mi][0] = *(const v8s*)&ba_[mi * 1024 + col0];                     \
        af_[mi][1] = *(const v8s*)&ba_[mi * 1024 + col1];                     \
    }                                                                         \
    _Pragma("unroll")                                                         \
    for (int ni = 0; ni < 2; ++ni) {                                          \
        bf_[ni][0] = *(const v8s*)&bb_[ni * 1024 + col0];                     \
        bf_[ni][1] = *(const v8s*)&bb_[ni * 1024 + col1];                     \
    }                                                                         \
    __builtin_amdgcn_s_setprio(1);                                            \
    _Pragma("unroll")                                                         \
    for (int mi = 0; mi < 4; ++mi)                                            \
      _Pragma("unroll")                                                       \
      for (int ni = 0; ni < 2; ++ni) {                                        \
        acc[mi][ni] = __builtin_amdgcn_mfma_f32_16x16x32_bf16(                \
            af_[mi][0], bf_[ni][0], acc[mi][ni], 0, 0, 0);                    \
        acc[mi][ni] = __builtin_amdgcn_mfma_f32_16x16x32_bf16(                \
            af_[mi][1], bf_[ni][1], acc[mi][ni], 0, 0, 0);                    \
      }                                                                       \
    __builtin_amdgcn_s_setprio(0);                                            \
}

__global__ __launch_bounds__(512, 4) void gates_mm_128w8(
    const ushort* __restrict__ A, const ushort* __restrict__ Bm,
    const float* __restrict__ cs,
    const float* __restrict__ bxi, const float* __restrict__ bxf,
    const float* __restrict__ bxc, const float* __restrict__ bxo,
    float* __restrict__ hid_out, float* __restrict__ cell_out,
    ushort* __restrict__ hidB)
{
    __shared__ ushort lds[32768];   // 64 KB: buf d at d*16384 (A 16KB | B 16KB)

    const int tid  = threadIdx.x;
    const int lane = tid & 63;
    const int w    = tid >> 6;          // 0..7
    const int wm = w >> 2;              // 0..1  (64-row M half)
    const int wn = w & 3;               // 0..3  (32-col N quarter)

    const int blkN = blockIdx.x;        // 0..63 (fast: A-panel reuse)
    const int blkM = blockIdx.y;        // 0..31

    // staging: source pre-swizzled (slot s of row r <- logical s^(r&7))
    const int srowS = tid >> 3;         // 0..63
    const int colES = (((tid & 7) ^ (srowS & 7)) << 3);
    const ushort* aSrc = A  + (size_t)(blkM * 128 + srowS) * K1 + colES;
    const ushort* bSrc = Bm + (size_t)(blkN * 128 + srowS) * K1 + colES;

    // fragment reads (R10/R12-verified)
    const int l15 = lane & 15, l4 = lane >> 4;
    const int fx = l15 & 7;
    const int col0 = ((l4      ^ fx) << 3);
    const int col1 = (((4 + l4) ^ fx) << 3);
    const int aRowU = (wm * 64 + l15) * 64;
    const int bRowU = (wn * 32 + l15) * 64;

    v4f acc[4][2];
    #pragma unroll
    for (int mi = 0; mi < 4; ++mi)
      #pragma unroll
      for (int ni = 0; ni < 2; ++ni) acc[mi][ni] = (v4f)0.f;

    STAGE(0, 0)
    #pragma unroll 1
    for (int t = 0; t < 47; ++t) {
        STAGE((t + 1) & 1, t + 1)
        asm volatile("s_waitcnt vmcnt(4)" ::: "memory");
        barrier_fenced();                 // buf t&1 writes landed for all waves
        COMPUTE(t & 1)
        barrier_fenced();                 // reads done before next overwrite
    }
    asm volatile("s_waitcnt vmcnt(0)" ::: "memory");
    barrier_fenced();
    COMPUTE(1)
    barrier_fenced();

    // ======================= fused LSTM epilogue =============================
    // csT/cT/hT [128][34] f32 (4352 floats each), hbT [128][36] bf16; 61.4 KB
    float*  csT = (float*)lds;             // floats      0..4351
    float*  cT  = (float*)lds + 4352;      // floats   4352..8703
    float*  hT  = (float*)lds + 8704;      // floats   8704..13055
    ushort* hbT = (ushort*)lds + 26112;    // ushorts 26112..30719

    const int g = lane & 3;
    const int Mb = blkM * 128;
    const int hbase = blkN * 32;

    int hl[2]; float biasj[2];
    #pragma unroll
    for (int ni = 0; ni < 2; ++ni) {
        hl[ni] = wn * 8 + ni * 4 + (l15 >> 2);      // 0..31 (quad-uniform)
        const float* bp = (g == 0) ? bxi : (g == 1) ? bxf : (g == 2) ? bxc : bxo;
        biasj[ni] = bp[hbase + hl[ni]];
    }

    const int erow = tid >> 2;           // 0..127
    const int ecol = (tid & 3) * 8;      // 0,8,16,24
    // coop-load cs tile [128][32] coalesced (2 float4 / thread)
    {
        const float* srcc = cs + (size_t)(Mb + erow) * H_ + hbase + ecol;
        *(float4*)&csT[erow * 34 + ecol]     = *(const float4*)(srcc);
        *(float4*)&csT[erow * 34 + ecol + 4] = *(const float4*)(srcc + 4);
    }
    __syncthreads();
    // quad 4x4 transpose epilogue: bias added pre-transpose (data gate-major),
    // then lane g owns row l4*4+g with v0..v3 = gates i,f,c,o of that row.
    #pragma unroll
    for (int mi = 0; mi < 4; ++mi) {
      #pragma unroll
      for (int ni = 0; ni < 2; ++ni) {
        float v0 = acc[mi][ni][0] + biasj[ni];
        float v1 = acc[mi][ni][1] + biasj[ni];
        float v2 = acc[mi][ni][2] + biasj[ni];
        float v3 = acc[mi][ni][3] + biasj[ni];
        {   // verified by element enumeration: new(l,r) = old(r,l) within quad
            float xx, yy;
            xx = (g & 1) ? v0 : v1; yy = __shfl_xor(xx, 1, 64);
            if (g & 1) v0 = yy; else v1 = yy;
            xx = (g & 1) ? v2 : v3; yy = __shfl_xor(xx, 1, 64);
            if (g & 1) v2 = yy; else v3 = yy;
            xx = (g & 2) ? v0 : v2; yy = __shfl_xor(xx, 2, 64);
            if (g & 2) v0 = yy; else v2 = yy;
            xx = (g & 2) ? v1 : v3; yy = __shfl_xor(xx, 2, 64);
            if (g & 2) v1 = yy; else v3 = yy;
        }
        const int ml = wm * 64 + mi * 16 + l4 * 4 + g;   // this lane's row
        const float Ig = sigm(v0), Fg = sigm(v1);
        const float Cg = tanh_f(v2), Og = sigm(v3);
        const float c_old = csT[ml * 34 + hl[ni]];
        const float c_new = Fg * c_old + Ig * Cg;
        const float h_new = Og * tanh_f(c_new);
        cT [ml * 34 + hl[ni]] = c_new;
        hT [ml * 34 + hl[ni]] = h_new;
        hbT[ml * 36 + hl[ni]] = f2bf(h_new);
      }
    }
    __syncthreads();
    // coop-store coalesced
    {
        const size_t gof = (size_t)(Mb + erow) * H_ + hbase + ecol;
        *(float4*)&cell_out[gof]     = *(const float4*)&cT[erow * 34 + ecol];
        *(float4*)&cell_out[gof + 4] = *(const float4*)&cT[erow * 34 + ecol + 4];
        *(float4*)&hid_out [gof]     = *(const float4*)&hT[erow * 34 + ecol];
        *(float4*)&hid_out [gof + 4] = *(const float4*)&hT[erow * 34 + ecol + 4];
        *(uint2*)&hidB[gof]          = *(const uint2*)&hbT[erow * 36 + ecol];
        *(uint2*)&hidB[gof + 4]      = *(const uint2*)&hbT[erow * 36 + ecol + 4];
    }
}

// ---------------------------------------------------------------------------
// GEMM2: out = hidB @ WhyB^T + b — R12 loop structure
// (128x128, BK=64, 512 threads / 8 waves, dbuf 64KB, vmcnt(4), fenced).
// ---------------------------------------------------------------------------

#define STAGE2(D, TT) {                                                       \
    const int kb_ = (TT) * 64;                                                \
    ushort* l0_ = (ushort*)lds + (D) * 16384 + tid * 8;                       \
    gload16(aSrc + kb_,             l0_);                                     \
    gload16(aSrc + 64 * H_ + kb_,   l0_ + 4096);                              \
    gload16(bSrc + kb_,             l0_ + 8192);                              \
    gload16(bSrc + 64 * H_ + kb_,   l0_ + 12288);                             \
}

__global__ __launch_bounds__(512, 4) void out_mm_bf16(
    const ushort* __restrict__ A, const ushort* __restrict__ Bm,
    const float* __restrict__ bw, float* __restrict__ out)
{
    __shared__ ushort lds[32768];

    const int tid  = threadIdx.x;
    const int lane = tid & 63;
    const int w    = tid >> 6;
    const int wm = w >> 2;              // 0..1
    const int wn = w & 3;               // 0..3

    const int blkN = blockIdx.x;        // 0..7
    const int blkM = blockIdx.y;        // 0..31

    const int srowS = tid >> 3;
    const int colES = (((tid & 7) ^ (srowS & 7)) << 3);
    const ushort* aSrc = A  + (size_t)(blkM * 128 + srowS) * H_ + colES;
    const ushort* bSrc = Bm + (size_t)(blkN * 128 + srowS) * H_ + colES;

    const int l15 = lane & 15, l4 = lane >> 4;
    const int fx = l15 & 7;
    const int col0 = ((l4      ^ fx) << 3);
    const int col1 = (((4 + l4) ^ fx) << 3);
    const int aRowU = (wm * 64 + l15) * 64;
    const int bRowU = (wn * 32 + l15) * 64;

    v4f acc[4][2];
    #pragma unroll
    for (int mi = 0; mi < 4; ++mi)
      #pragma unroll
      for (int ni = 0; ni < 2; ++ni) acc[mi][ni] = (v4f)0.f;

    STAGE2(0, 0)
    #pragma unroll 1
    for (int t = 0; t < 31; ++t) {
        STAGE2((t + 1) & 1, t + 1)
        asm volatile("s_waitcnt vmcnt(4)" ::: "memory");
        barrier_fenced();
        COMPUTE(t & 1)
        barrier_fenced();
    }
    asm volatile("s_waitcnt vmcnt(0)" ::: "memory");
    barrier_fenced();
    COMPUTE(1)

    // epilogue: bias + direct store
    #pragma unroll
    for (int mi = 0; mi < 4; ++mi) {
      #pragma unroll
      for (int r = 0; r < 4; ++r) {
        const int m = blkM * 128 + wm * 64 + mi * 16 + l4 * 4 + r;
        #pragma unroll
        for (int ni = 0; ni < 2; ++ni) {
            const int n = blkN * 128 + wn * 32 + ni * 16 + l15;
            out[(size_t)m * O_ + n] = acc[mi][ni][r] + bw[n];
        }
      }
    }
}

extern "C" void kernel_launch(void* const* d_in, const int* in_sizes, int n_in,
                              void* d_out, int out_size, void* d_ws, size_t ws_size,
                              hipStream_t stream) {
    const float* x   = (const float*)d_in[0];
    const float* hs  = (const float*)d_in[1];
    const float* cs  = (const float*)d_in[2];
    const float* Wxi = (const float*)d_in[3];
    const float* bxi = (const float*)d_in[4];
    const float* Whi = (const float*)d_in[5];
    const float* Wxf = (const float*)d_in[6];
    const float* bxf = (const float*)d_in[7];
    const float* Whf = (const float*)d_in[8];
    const float* Wxc = (const float*)d_in[9];
    const float* bxc = (const float*)d_in[10];
    const float* Whc = (const float*)d_in[11];
    const float* Wxo = (const float*)d_in[12];
    const float* bxo = (const float*)d_in[13];
    const float* Who = (const float*)d_in[14];
    const float* Why = (const float*)d_in[15];
    const float* bwy = (const float*)d_in[16];

    float* out      = (float*)d_out;
    float* hid_out  = out + (size_t)B_ * O_;
    float* cell_out = hid_out + (size_t)B_ * H_;

    const size_t szW = (size_t)N1 * K1;
    const size_t szX = (size_t)B_ * K1;
    const size_t szY = (size_t)O_ * H_;

    ushort* Wcat = (ushort*)d_ws;
    ushort* Xcat = Wcat + szW;
    ushort* WhyB = Xcat + szX;
    ushort* HidB = WhyB + szY;

    convert_all<<<dim3(N1 + B_ + O_), 384, 0, stream>>>(
        Wxi, Whi, Wxf, Whf, Wxc, Whc, Wxo, Who, x, hs, Why, Wcat, Xcat, WhyB);

    gates_mm_128w8<<<dim3(N1 / 128, B_ / 128), 512, 0, stream>>>(
        Xcat, Wcat, cs, bxi, bxf, bxc, bxo, hid_out, cell_out, HidB);
    out_mm_bf16<<<dim3(O_ / 128, B_ / 128), 512, 0, stream>>>(
        HidB, WhyB, bwy, out);
}